// Round 18
// baseline (185.705 us; speedup 1.0000x reference)
//
#include <hip/hip_runtime.h>
#include <hip/hip_bf16.h>
#include <cstdint>
#include <cstddef>

// Problem dims (fixed): B=4, NI=NO=256, DIN=DQ=DH=DOUT=256.
// out[b,i,j,:] = gelu(u[b,i,:] + v[b,j,:]) @ W2 + b2
//   u = (x@W_pre + b_pre)@W1[:256] + b1   (b1 folded into u)
//   v = (query@W_emb + b_emb)@W1[256:]   (row-major)
//   W2F = W2 in fragment-major granules: granule (g,n) = bf16 W2[8g..8g+7][n]

typedef __bf16  bf16x8 __attribute__((ext_vector_type(8)));
typedef float   f32x16 __attribute__((ext_vector_type(16)));

// tanh-approx gelu with exp2 constant pre-folded:
// gelu(x) ~= x / (1 + exp2(x*(-2.3022072 - 0.1029433*x^2)))
__device__ __forceinline__ float fast_gelu(float x) {
    const float x2 = x * x;
    const float m  = __builtin_fmaf(x2, -0.1029433f, -2.3022072f);
    const float e  = __builtin_amdgcn_exp2f(x * m);
    return x * __builtin_amdgcn_rcpf(1.0f + e);
}

// ---------------------------------------------------------------------------
// Prep kernel (one launch) — unchanged from round 14 (passed).
//   blocks [0,256):   u rows — x path (4 rows/block)
//   blocks [256,512): v rows — query path (row-major)
//   blocks [512,576): W2F granules: w2f[(g*256+n)*8 + e] = bf16(W2[8g+e][n])
// ---------------------------------------------------------------------------
__global__ __launch_bounds__(256) void prep_kernel(
    const float* __restrict__ x, const float* __restrict__ query,
    const float* __restrict__ W_pre, const float* __restrict__ b_pre,
    const float* __restrict__ W_emb, const float* __restrict__ b_emb,
    const float* __restrict__ W1, const float* __restrict__ b1,
    const float* __restrict__ W2,
    float* __restrict__ u, float* __restrict__ v,
    unsigned short* __restrict__ w2f)
{
    const int b = blockIdx.x;
    const int t = threadIdx.x;

    if (b >= 512) {                       // W2 -> fragment-major bf16 granules
        const int n0 = (b - 512) * 4;     // t = k
        const float4 wv = *reinterpret_cast<const float4*>(W2 + (size_t)t * 256 + n0);
        const float vals[4] = {wv.x, wv.y, wv.z, wv.w};
        const int g = t >> 3, e = t & 7;
#pragma unroll
        for (int j = 0; j < 4; ++j) {
            const __bf16 bv = (__bf16)vals[j];
            w2f[((size_t)(g * 256 + n0 + j)) * 8 + e] =
                __builtin_bit_cast(unsigned short, bv);
        }
        return;
    }

    const bool isq = (b >= 256);
    const float* __restrict__ A   = isq ? query : x;
    const float* __restrict__ Wa  = isq ? W_emb : W_pre;
    const float* __restrict__ ba  = isq ? b_emb : b_pre;
    const float* __restrict__ W1p = isq ? (W1 + 256 * 256) : W1;
    float* __restrict__ outp      = isq ? v : u;
    const int r0 = (isq ? (b - 256) : b) * 4;

    __shared__ float as[4][256];
    __shared__ float xs[4][256];

#pragma unroll
    for (int r = 0; r < 4; ++r)
        as[r][t] = A[(size_t)(r0 + r) * 256 + t];
    __syncthreads();

    float acc[4] = {0.f, 0.f, 0.f, 0.f};
    {
        float wcur[8];
#pragma unroll
        for (int q = 0; q < 8; ++q) wcur[q] = Wa[(size_t)q * 256 + t];
        for (int k0 = 0; k0 < 248; k0 += 8) {
            float wnxt[8];
#pragma unroll
            for (int q = 0; q < 8; ++q)
                wnxt[q] = Wa[(size_t)(k0 + 8 + q) * 256 + t];
#pragma unroll
            for (int q = 0; q < 8; ++q)
#pragma unroll
                for (int r = 0; r < 4; ++r)
                    acc[r] = __builtin_fmaf(as[r][k0 + q], wcur[q], acc[r]);
#pragma unroll
            for (int q = 0; q < 8; ++q) wcur[q] = wnxt[q];
        }
#pragma unroll
        for (int q = 0; q < 8; ++q)
#pragma unroll
            for (int r = 0; r < 4; ++r)
                acc[r] = __builtin_fmaf(as[r][248 + q], wcur[q], acc[r]);
    }
    const float bav = ba[t];
#pragma unroll
    for (int r = 0; r < 4; ++r) xs[r][t] = acc[r] + bav;
    __syncthreads();

    float acc2[4] = {0.f, 0.f, 0.f, 0.f};
    {
        float wcur[8];
#pragma unroll
        for (int q = 0; q < 8; ++q) wcur[q] = W1p[(size_t)q * 256 + t];
        for (int k0 = 0; k0 < 248; k0 += 8) {
            float wnxt[8];
#pragma unroll
            for (int q = 0; q < 8; ++q)
                wnxt[q] = W1p[(size_t)(k0 + 8 + q) * 256 + t];
#pragma unroll
            for (int q = 0; q < 8; ++q)
#pragma unroll
                for (int r = 0; r < 4; ++r)
                    acc2[r] = __builtin_fmaf(xs[r][k0 + q], wcur[q], acc2[r]);
#pragma unroll
            for (int q = 0; q < 8; ++q) wcur[q] = wnxt[q];
        }
#pragma unroll
        for (int q = 0; q < 8; ++q)
#pragma unroll
            for (int r = 0; r < 4; ++r)
                acc2[r] = __builtin_fmaf(xs[r][248 + q], wcur[q], acc2[r]);
    }
    const float b1v = isq ? 0.f : b1[t];
#pragma unroll
    for (int r = 0; r < 4; ++r)
        outp[(size_t)(r0 + r) * 256 + t] = acc2[r] + b1v;
}

// ---------------------------------------------------------------------------
// Fused main kernel — 1-WAVE blocks, ZERO barriers, max phase diversity.
//
// 8192 blocks x 64 threads. Block = one wave owning 32 j-rows x 256 cols of
// one (b,i) tile: tile = bid>>3, slab = bid&7 (j rows slab*32..+32).
// 12 independent 1-wave programs per CU (VGPR ~135, launch_bounds(64,3);
// LDS 4 KB/block) — each at a different point in its lifetime, so stores,
// V loads, gelu VALU and MFMA are co-issued chip-wide BY CONSTRUCTION.
// This attacks the duty-cycle loss (phase-locked cohorts leaving the write
// pipe idle during phase 1) that R17's register-heavy fusion failed to fix.
//
// Phase 1 (4 chunks, no barriers): coalesced V loads (lane -> k-pair d=l31,
// 2 whole rows per instr: row = 2p+hi) -> gelu once -> XOR-swizzled
// ds_write into the block's PRIVATE 4 KB hlds -> ds_read_b128 A-granules
// (intra-wave: in-order DS pipe + compiler lgkmcnt; no sync needed) ->
// af[16] = full-K A-fragments (64 VGPR).
// Phase 2 (8 col-groups): 16 independent dwordx4 B-granule loads DIRECT
// from W2F (128 KB, L2-resident; ~200cy latency hidden by 11 other waves)
// -> 16 MFMA -> 16 dword stores (col-outer: stores spread in 8 batches).
//
// mfma_f32_32x32x16_bf16 layouts (gfx950):
//   A: lane l holds A[l&31][(l>>5)*8 + e]
//   B: lane l holds B[(l>>5)*8 + e][l&31]
//   D: lane l reg r holds D[(r&3) + 8*(r>>2) + 4*(l>>5)][l&31]
// ---------------------------------------------------------------------------
__global__ __launch_bounds__(64, 3) void fused_kernel(
    const float* __restrict__ U, const float* __restrict__ V,
    const unsigned short* __restrict__ W2F, const float* __restrict__ b2,
    float* __restrict__ out)
{
    __shared__ uint4 hlds[256];    // 4 KB: H chunk [32 r][8 g], swizzled
    unsigned int* const h32 = reinterpret_cast<unsigned int*>(hlds);

    const int t   = threadIdx.x;   // == lane (1 wave)
    const int l31 = t & 31;
    const int hi  = t >> 5;        // 0..1

    const int bid  = blockIdx.x;
    const int tile = bid >> 3;     // 0..1023 = (bb, ii)
    const int slab = bid & 7;      // j-slab: rows slab*32 .. +32
    const int bb   = tile >> 8;

    const float* __restrict__ urow  = U + (size_t)tile * 256;
    const float* __restrict__ vbase = V + ((size_t)(bb * 256 + slab * 32)) * 256;

    const int d    = l31;          // k-pair index within chunk (k = kk+2d,+1)
    const int arow = l31;          // A-row within the 32-row slab

    // ---- phase 1: af[16] = A-frags for full K=256; no barriers ----
    bf16x8 af[16];
#pragma unroll
    for (int c = 0; c < 4; ++c) {
        const int kk = c * 64;
        const float2 u2 = *reinterpret_cast<const float2*>(urow + kk + 2 * d);
        float2 vv[16];
#pragma unroll
        for (int p = 0; p < 16; ++p) {
            const int row = p * 2 + hi;            // 2 whole rows per instr
            vv[p] = *reinterpret_cast<const float2*>(
                vbase + (size_t)row * 256 + kk + 2 * d);
        }
#pragma unroll
        for (int p = 0; p < 16; ++p) {
            const int row = p * 2 + hi;
            union { unsigned int u32; __bf16 h[2]; } pk;
            pk.h[0] = (__bf16)fast_gelu(u2.x + vv[p].x);
            pk.h[1] = (__bf16)fast_gelu(u2.y + vv[p].y);
            h32[row * 32 + (((d >> 2) ^ (row & 7)) << 2) + (d & 3)] = pk.u32;
        }
        // intra-wave ds_write -> ds_read: in-order DS pipe + lgkmcnt
#pragma unroll
        for (int s = 0; s < 4; ++s) {
            const int gl = 2 * s + hi;             // granule within chunk
            af[c * 4 + s] = __builtin_bit_cast(
                bf16x8, hlds[arow * 8 + (gl ^ (arow & 7))]);
        }
    }

    // hoist b2 for all col-groups
    float bvv[8];
#pragma unroll
    for (int cg = 0; cg < 8; ++cg) bvv[cg] = b2[cg * 32 + l31];

    const size_t obase = ((size_t)tile << 16) + (size_t)(slab * 32) * 256;

    // ---- phase 2: col-outer, B direct from L2, stores spread ----
#pragma unroll
    for (int cg = 0; cg < 8; ++cg) {
        f32x16 acc = (f32x16)0.f;
#pragma unroll
        for (int S = 0; S < 16; ++S) {
            const uint4 braw = *reinterpret_cast<const uint4*>(
                W2F + ((size_t)((2 * S + hi) * 256 + cg * 32 + l31)) * 8);
            const bf16x8 bf_ = __builtin_bit_cast(bf16x8, braw);
            acc = __builtin_amdgcn_mfma_f32_32x32x16_bf16(af[S], bf_, acc, 0, 0, 0);
        }

        const int col = cg * 32 + l31;
#pragma unroll
        for (int rr = 0; rr < 16; ++rr) {
            const int row = 4 * hi + (rr & 3) + 8 * (rr >> 2);
            out[obase + (size_t)row * 256 + col] = acc[rr] + bvv[cg];
        }
    }
}

// ---------------------------------------------------------------------------
extern "C" void kernel_launch(void* const* d_in, const int* in_sizes, int n_in,
                              void* d_out, int out_size, void* d_ws, size_t ws_size,
                              hipStream_t stream)
{
    const float* x     = (const float*)d_in[0];
    const float* query = (const float*)d_in[1];
    const float* W_pre = (const float*)d_in[2];
    const float* b_pre = (const float*)d_in[3];
    const float* W_emb = (const float*)d_in[4];
    const float* b_emb = (const float*)d_in[5];
    const float* W1    = (const float*)d_in[6];
    const float* b1    = (const float*)d_in[7];
    const float* W2    = (const float*)d_in[8];
    const float* b2    = (const float*)d_in[9];
    float* out = (float*)d_out;

    char* ws = (char*)d_ws;
    float* u            = (float*)(ws);                          // 1 MB
    float* v            = (float*)(ws + (1 << 20));              // 1 MB
    unsigned short* w2f = (unsigned short*)(ws + 2 * (1 << 20)); // 128 KB

    prep_kernel<<<576, 256, 0, stream>>>(x, query, W_pre, b_pre, W_emb, b_emb,
                                         W1, b1, W2, u, v, w2f);
    fused_kernel<<<8192, 64, 0, stream>>>(u, v, w2f, b2, out);
}

// Round 19
// 90.459 us; speedup vs baseline: 2.0529x; 2.0529x over previous
//
#include <hip/hip_runtime.h>
#include <hip/hip_bf16.h>
#include <cstdint>
#include <cstddef>

// Problem dims (fixed): B=4, NI=NO=256, DIN=DQ=DH=DOUT=256.
// out[b,i,j,:] = gelu(u[b,i,:] + v[b,j,:]) @ W2 + b2
//   u = (x@W_pre + b_pre)@W1[:256] + b1   (b1 folded into u)
//   v = (query@W_emb + b_emb)@W1[256:]   (row-major)
//   W2F = W2 in fragment-major granules: granule (g,n) = bf16 W2[8g..8g+7][n]

typedef __bf16  bf16x8 __attribute__((ext_vector_type(8)));
typedef float   f32x16 __attribute__((ext_vector_type(16)));

// tanh-approx gelu with exp2 constant pre-folded:
// gelu(x) ~= x / (1 + exp2(x*(-2.3022072 - 0.1029433*x^2)))
__device__ __forceinline__ float fast_gelu(float x) {
    const float x2 = x * x;
    const float m  = __builtin_fmaf(x2, -0.1029433f, -2.3022072f);
    const float e  = __builtin_amdgcn_exp2f(x * m);
    return x * __builtin_amdgcn_rcpf(1.0f + e);
}

// ---------------------------------------------------------------------------
// Prep kernel (one launch):
//   blocks [0,256):   u rows — x path (4 rows/block)
//   blocks [256,512): v rows — query path (row-major)
//   blocks [512,576): W2F granules: w2f[(g*256+n)*8 + e] = bf16(W2[8g+e][n])
// 8-deep register prefetch in both GEMM k-loops (~10 us total).
// ---------------------------------------------------------------------------
__global__ __launch_bounds__(256) void prep_kernel(
    const float* __restrict__ x, const float* __restrict__ query,
    const float* __restrict__ W_pre, const float* __restrict__ b_pre,
    const float* __restrict__ W_emb, const float* __restrict__ b_emb,
    const float* __restrict__ W1, const float* __restrict__ b1,
    const float* __restrict__ W2,
    float* __restrict__ u, float* __restrict__ v,
    unsigned short* __restrict__ w2f)
{
    const int b = blockIdx.x;
    const int t = threadIdx.x;

    if (b >= 512) {                       // W2 -> fragment-major bf16 granules
        const int n0 = (b - 512) * 4;     // t = k
        const float4 wv = *reinterpret_cast<const float4*>(W2 + (size_t)t * 256 + n0);
        const float vals[4] = {wv.x, wv.y, wv.z, wv.w};
        const int g = t >> 3, e = t & 7;
#pragma unroll
        for (int j = 0; j < 4; ++j) {
            const __bf16 bv = (__bf16)vals[j];
            w2f[((size_t)(g * 256 + n0 + j)) * 8 + e] =
                __builtin_bit_cast(unsigned short, bv);
        }
        return;
    }

    const bool isq = (b >= 256);
    const float* __restrict__ A   = isq ? query : x;
    const float* __restrict__ Wa  = isq ? W_emb : W_pre;
    const float* __restrict__ ba  = isq ? b_emb : b_pre;
    const float* __restrict__ W1p = isq ? (W1 + 256 * 256) : W1;
    float* __restrict__ outp      = isq ? v : u;
    const int r0 = (isq ? (b - 256) : b) * 4;

    __shared__ float as[4][256];
    __shared__ float xs[4][256];

#pragma unroll
    for (int r = 0; r < 4; ++r)
        as[r][t] = A[(size_t)(r0 + r) * 256 + t];
    __syncthreads();

    float acc[4] = {0.f, 0.f, 0.f, 0.f};
    {
        float wcur[8];
#pragma unroll
        for (int q = 0; q < 8; ++q) wcur[q] = Wa[(size_t)q * 256 + t];
        for (int k0 = 0; k0 < 248; k0 += 8) {
            float wnxt[8];
#pragma unroll
            for (int q = 0; q < 8; ++q)
                wnxt[q] = Wa[(size_t)(k0 + 8 + q) * 256 + t];
#pragma unroll
            for (int q = 0; q < 8; ++q)
#pragma unroll
                for (int r = 0; r < 4; ++r)
                    acc[r] = __builtin_fmaf(as[r][k0 + q], wcur[q], acc[r]);
#pragma unroll
            for (int q = 0; q < 8; ++q) wcur[q] = wnxt[q];
        }
#pragma unroll
        for (int q = 0; q < 8; ++q)
#pragma unroll
            for (int r = 0; r < 4; ++r)
                acc[r] = __builtin_fmaf(as[r][248 + q], wcur[q], acc[r]);
    }
    const float bav = ba[t];
#pragma unroll
    for (int r = 0; r < 4; ++r) xs[r][t] = acc[r] + bav;
    __syncthreads();

    float acc2[4] = {0.f, 0.f, 0.f, 0.f};
    {
        float wcur[8];
#pragma unroll
        for (int q = 0; q < 8; ++q) wcur[q] = W1p[(size_t)q * 256 + t];
        for (int k0 = 0; k0 < 248; k0 += 8) {
            float wnxt[8];
#pragma unroll
            for (int q = 0; q < 8; ++q)
                wnxt[q] = W1p[(size_t)(k0 + 8 + q) * 256 + t];
#pragma unroll
            for (int q = 0; q < 8; ++q)
#pragma unroll
                for (int r = 0; r < 4; ++r)
                    acc2[r] = __builtin_fmaf(xs[r][k0 + q], wcur[q], acc2[r]);
#pragma unroll
            for (int q = 0; q < 8; ++q) wcur[q] = wnxt[q];
        }
#pragma unroll
        for (int q = 0; q < 8; ++q)
#pragma unroll
            for (int r = 0; r < 4; ++r)
                acc2[r] = __builtin_fmaf(xs[r][248 + q], wcur[q], acc2[r]);
    }
    const float b1v = isq ? 0.f : b1[t];
#pragma unroll
    for (int r = 0; r < 4; ++r)
        outp[(size_t)(r0 + r) * 256 + t] = acc2[r] + b1v;
}

// ---------------------------------------------------------------------------
// Fused main kernel — EXACT round-14 configuration (session best: 90.8 us).
// Column-outer with persistent A-frags; stores spread in 8 batches.
//
// Block = 256 thr = 4 waves; tile = 128 j-rows x 256 cols; 2048 blocks
// (tile = bid>>1 is (b,i); jh = bid&1). Wave w owns rows [w*32,+32) x all
// cols.
//
// Phase 1 (4 chunks of 64 k): coalesced V/U loads -> gelu once -> swizzled
// ds_write H[128r][64k] (16 KB) -> barrier -> each wave ds_read_b128 its
// 4 A-granules -> af[16] (64 VGPR, all K resident) -> barrier.
// Phase 2 (8 col-groups): stage cg's W2F B-tile [32 g][32 c] (16 KB,
// double-buffered) via global_load_lds w16 (linear src+dst); 16
// ds_read_b128 + 16 MFMA into ONE f32x16 acc; store the 32-col slice
// immediately (plain stores); barrier. Stores issue in 8 evenly spaced
// batches overlapping the next cg's staging+MFMA.
//
// LDS 48 KB, ~135 VGPR, launch_bounds(256,3) -> 3 blocks/CU, 12 waves/CU.
//
// Structural constraint (measured across R5/R9/R11/R13/R16/R17/R18): the
// 43 us HBM write floor + phase-cohort write-idle during A-frag production
// caps this op at ~80 us fused; every attempt to buy more overlap lost an
// occupancy/residency property worth more than the overlap gained.
//
// mfma_f32_32x32x16_bf16 layouts (gfx950):
//   A: lane l holds A[l&31][(l>>5)*8 + e]
//   B: lane l holds B[(l>>5)*8 + e][l&31]
//   D: lane l reg r holds D[(r&3) + 8*(r>>2) + 4*(l>>5)][l&31]
// ---------------------------------------------------------------------------
__global__ __launch_bounds__(256, 3) void fused_kernel(
    const float* __restrict__ U, const float* __restrict__ V,
    const unsigned short* __restrict__ W2F, const float* __restrict__ b2,
    float* __restrict__ out)
{
    __shared__ uint4 hlds[1024];      // 16 KB: H chunk [128 r][8 g], swizzled
    __shared__ uint4 blds[2][1024];   // 2x16 KB: B tile [32 g][32 c], linear
    unsigned int* const h32 = reinterpret_cast<unsigned int*>(hlds);

    const int t    = threadIdx.x;
    const int lane = t & 63;
    const int w    = t >> 6;       // 0..3
    const int l31  = lane & 31;
    const int hi   = lane >> 5;    // 0..1

    const int bid  = blockIdx.x;
    const int tile = bid >> 1;     // 0..1023 = (bb, ii)
    const int jh   = bid & 1;
    const int bb   = tile >> 8;

    const float* __restrict__ urow  = U + (size_t)tile * 256;
    const float* __restrict__ vbase = V + ((size_t)(bb * 256 + jh * 128)) * 256;

    // H-compute mapping: d = k-pair (k = kk+2d, 2d+1); rows rb + 8*p.
    const int d  = t & 31;
    const int rb = t >> 5;         // 0..7

    auto stage_b = [&](int cg, int buf) {
#pragma unroll
        for (int it = 0; it < 4; ++it) {
            const int idx = it * 256 + t;      // 0..1023 linear granule
            const int g   = idx >> 5;          // 0..31
            const int c   = idx & 31;          // 0..31 local col
            __builtin_amdgcn_global_load_lds(
                (const __attribute__((address_space(1))) unsigned int*)
                    (W2F + ((size_t)(g * 256 + cg * 32 + c)) * 8),
                (__attribute__((address_space(3))) unsigned int*)
                    (&blds[buf][idx]),
                16, 0, 0);
        }
    };

    // stage B tile for cg=0 early: hides W2F L2 latency under ALL of phase 1
    stage_b(0, 0);

    // ---- phase 1: produce af[16] = A-frags for the full K=256 ----
    bf16x8 af[16];
#pragma unroll
    for (int c = 0; c < 4; ++c) {
        const int kk = c * 64;
        const float2 u2 = *reinterpret_cast<const float2*>(urow + kk + 2 * d);
        float2 vv[16];
#pragma unroll
        for (int p = 0; p < 16; ++p) {
            const int row = rb + p * 8;        // 2 whole rows per wave-instr
            vv[p] = *reinterpret_cast<const float2*>(
                vbase + (size_t)row * 256 + kk + 2 * d);
        }
#pragma unroll
        for (int p = 0; p < 16; ++p) {
            const int row = rb + p * 8;
            union { unsigned int u32; __bf16 h[2]; } pk;
            pk.h[0] = (__bf16)fast_gelu(u2.x + vv[p].x);
            pk.h[1] = (__bf16)fast_gelu(u2.y + vv[p].y);
            h32[row * 32 + (((d >> 2) ^ (row & 7)) << 2) + (d & 3)] = pk.u32;
        }
        __syncthreads();                       // H chunk ready (drains vm+lgkm)
        const int arow = w * 32 + l31;
#pragma unroll
        for (int s = 0; s < 4; ++s) {
            const int gl = 2 * s + hi;         // granule within chunk
            af[c * 4 + s] = __builtin_bit_cast(
                bf16x8, hlds[arow * 8 + (gl ^ (arow & 7))]);
        }
        __syncthreads();                       // reads done; chunk reusable
    }

    // hoist b2 for all col-groups
    float bvv[8];
#pragma unroll
    for (int cg = 0; cg < 8; ++cg) bvv[cg] = b2[cg * 32 + l31];

    const size_t obase = ((size_t)tile << 16) + (size_t)(jh * 128 + w * 32) * 256;

    // ---- phase 2: col-outer MFMA + immediate stores ----
#pragma unroll
    for (int cg = 0; cg < 8; ++cg) {
        if (cg < 7) stage_b(cg + 1, (cg + 1) & 1);

        f32x16 acc = (f32x16)0.f;
#pragma unroll
        for (int S = 0; S < 16; ++S) {
            const bf16x8 bf_ = __builtin_bit_cast(
                bf16x8, blds[cg & 1][(2 * S + hi) * 32 + l31]);
            acc = __builtin_amdgcn_mfma_f32_32x32x16_bf16(af[S], bf_, acc, 0, 0, 0);
        }

        const int col = cg * 32 + l31;
#pragma unroll
        for (int rr = 0; rr < 16; ++rr) {
            const int row = 4 * hi + (rr & 3) + 8 * (rr >> 2);
            out[obase + (size_t)row * 256 + col] = acc[rr] + bvv[cg];
        }
        __syncthreads();   // all waves done with blds[cg&1]; cg+1 staged
    }
}

// ---------------------------------------------------------------------------
extern "C" void kernel_launch(void* const* d_in, const int* in_sizes, int n_in,
                              void* d_out, int out_size, void* d_ws, size_t ws_size,
                              hipStream_t stream)
{
    const float* x     = (const float*)d_in[0];
    const float* query = (const float*)d_in[1];
    const float* W_pre = (const float*)d_in[2];
    const float* b_pre = (const float*)d_in[3];
    const float* W_emb = (const float*)d_in[4];
    const float* b_emb = (const float*)d_in[5];
    const float* W1    = (const float*)d_in[6];
    const float* b1    = (const float*)d_in[7];
    const float* W2    = (const float*)d_in[8];
    const float* b2    = (const float*)d_in[9];
    float* out = (float*)d_out;

    char* ws = (char*)d_ws;
    float* u            = (float*)(ws);                          // 1 MB
    float* v            = (float*)(ws + (1 << 20));              // 1 MB
    unsigned short* w2f = (unsigned short*)(ws + 2 * (1 << 20)); // 128 KB

    prep_kernel<<<576, 256, 0, stream>>>(x, query, W_pre, b_pre, W_emb, b_emb,
                                         W1, b1, W2, u, v, w2f);
    fused_kernel<<<2048, 256, 0, stream>>>(u, v, w2f, b2, out);
}